// Round 12
// baseline (6216.511 us; speedup 1.0000x reference)
//
#include <hip/hip_runtime.h>
#include <hip/hip_fp16.h>

typedef _Float16 f16;
typedef _Float16 f16x8 __attribute__((ext_vector_type(8)));
typedef _Float16 f16x4 __attribute__((ext_vector_type(4)));
typedef float    f32x4 __attribute__((ext_vector_type(4)));

#define TT 512
#define BB 256
#define HH 256

// ---- workspace byte offsets ----
#define O_WFRAG_ENC 0u
#define O_WFRAG_M   393216u
#define O_WFRAG_P   786432u
#define O_WFRAG_GI  1179648u
#define O_HE_ST     1966080u
#define O_HM_ST     2097152u
#define O_HP_ST     2228224u
#define O_HPSUM     2359296u
#define O_DYN       2621440u
#define DYN_PER_STEP 917504u   // he_buf 131072 + gi_buf 786432 per step

__device__ __forceinline__ float sigf(float x){ return 1.0f/(1.0f+__expf(-x)); }
__device__ __forceinline__ float tanh_(float x){
  float xc = fminf(fmaxf(x,-15.f),15.f);
  float e  = __expf(2.f*xc);
  return (e-1.f)/(e+1.f);
}
// XOR-swizzled element index into a [32][256] f16 tile (16B granules ^ row&7)
__device__ __forceinline__ int hswz(int row, int j){
  return row*256 + ((((j>>3) ^ (row&7)))<<3) + (j&7);
}
// async global->LDS, 16B per lane (dest = wave-uniform base + lane*16)
__device__ __forceinline__ void gload_lds16(const void* g, void* l){
  __builtin_amdgcn_global_load_lds(
      (const __attribute__((address_space(1))) unsigned int*)g,
      (__attribute__((address_space(3))) unsigned int*)l, 16, 0, 0);
}
// scheduling fences (rule #18: sched_barrier(0) is the fence that holds)
#define SB()        __builtin_amdgcn_sched_barrier(0)
#define LGKM0_SB()  do{ asm volatile("s_waitcnt lgkmcnt(0)" ::: "memory"); SB(); }while(0)
#define WAITV6_SB() do{ asm volatile("s_waitcnt vmcnt(6)"   ::: "memory"); SB(); }while(0)

// =====================================================================
// PREP: weights -> f16 fragment buffers (rec: ks-major chunks), states
// =====================================================================
__global__ void prep_kernel(
    const float* __restrict__ enc_whh, const float* __restrict__ mdec_whh,
    const float* __restrict__ pdec_whh, const float* __restrict__ mdec_wih,
    const float* __restrict__ pdec_wih,
    const float* __restrict__ h0e, const float* __restrict__ h0m, const float* __restrict__ h0p,
    f16* __restrict__ wfrag_enc, f16* __restrict__ wfrag_m, f16* __restrict__ wfrag_p,
    f16* __restrict__ wfrag_gi,
    f16* __restrict__ he_st, f16* __restrict__ hm_st, f16* __restrict__ hp_st,
    float* __restrict__ hpsum)
{
  int idx = blockIdx.x*256 + threadIdx.x;
  const int NW = 8*48*64*8; // 196608 per recurrence buffer (ks-major chunks)
  if (idx < 3*NW){
    int b = idx / NW, e = idx % NW;
    int jj = e & 7, l = (e>>3)&63, c = e>>9;    // c in [0,384)
    int ks = c / 48, rem = c % 48;
    int w = rem / 3, g = rem % 3;
    int row = g*256 + w*16 + (l&15);
    int col = ks*32 + (l>>4)*8 + jj;
    const float* W = (b==0)?enc_whh:((b==1)?mdec_whh:pdec_whh);
    f16* D = (b==0)?wfrag_enc:((b==1)?wfrag_m:wfrag_p);
    D[e] = (f16)W[row*256+col];
    return;
  }
  idx -= 3*NW;
  const int NG = 96*8*64*8; // 393216
  if (idx < NG){
    int e = idx;
    int jj = e&7, l=(e>>3)&63, ks=(e>>9)&7, mt = e>>12;
    int row = mt*16 + (l&15);
    int col = ks*32 + (l>>4)*8 + jj;
    float v = (row < 768) ? mdec_wih[row*256+col] : pdec_wih[(row-768)*256+col];
    wfrag_gi[e] = (f16)v;
    return;
  }
  idx -= NG;
  if (idx < 65536){
    he_st[idx] = (f16)h0e[idx];
    hm_st[idx] = (f16)h0m[idx];
    hp_st[idx] = (f16)h0p[idx];
    hpsum[idx] = 0.f;
  }
}

// =====================================================================
// Recurrence core. MODE 0=encoder, 1=mask-dec, 2=pred-dec.
// 24 WGs total: 3 recs x 8 row-groups of 32 batch rows. 512 threads.
// W_hh streamed L2->LDS per step (8 ks-chunks of 48 KB, dbuf, r11's
// proven fence pattern), but each chunk now feeds 12 MFMAs/wave
// (2 jb x 3 gates x 2 row-tiles) -- DMA RTT hidden by real work.
// h is SINGLE-buffered in LDS; barrier #1 separates MFMA A-reads from
// gate writes, barrier #2 publishes the new h. psum lives in LDS.
// =====================================================================
template<int MODE>
__device__ __forceinline__ void gru_run(
  int g32, int slice, int SL,
  const f16* __restrict__ wfrag,
  const float* __restrict__ bih, const float* __restrict__ bhh,
  const float* __restrict__ enc_wih,
  const float* __restrict__ seq, const float* __restrict__ dpad,
  const f16* __restrict__ gi_buf,
  f16* __restrict__ h_state,
  f16* __restrict__ he_buf,
  const float* __restrict__ mlin_w, const float* __restrict__ mlin_b,
  float* __restrict__ out_mask,
  float* __restrict__ hpsum,
  unsigned char* smem)
{
  const int tid = threadIdx.x;       // 512
  const int lane = tid & 63;
  const int wid  = tid >> 6;         // 0..7
  const int l15  = lane & 15;
  const int lhi  = lane >> 4;
  const int bi0  = lhi*4;
  const int b0   = g32*32;
  const int w0   = wid*2;            // first owned j-block
  const int GOFF = (MODE==2) ? 768 : 0;

  f16* wbuf  = (f16*)smem;                      // [2][24576] chunk dbuf (96 KB)
  f16* hbuf  = (f16*)(smem + 98304);            // [32*256] swizzled h (16 KB)
  float* ps  = (float*)(smem + 114688);         // [32][256] psum (32 KB, pdec)
  float* mred= (float*)(smem + 147456);         // [8][32] (mdec)
  float* xb  = (float*)(smem + 148480);         // [2][32] (enc)

  // ---- per-lane biases
  float cr[2], cz[2], cnh[2], cni[2];
  float wr_[2], wz_[2], wn_[2], mw[2];
  #pragma unroll
  for (int q=0;q<2;++q){
    const int j = (w0+q)*16 + l15;
    if (MODE==0){
      cr[q]  = bih[j]     + bhh[j];
      cz[q]  = bih[256+j] + bhh[256+j];
      cnh[q] = bhh[512+j];
      cni[q] = bih[512+j];
      wr_[q]=enc_wih[j]; wz_[q]=enc_wih[256+j]; wn_[q]=enc_wih[512+j];
    } else {
      cr[q]  = bhh[j];
      cz[q]  = bhh[256+j];
      cnh[q] = bhh[512+j];
      cni[q] = 0.f;
    }
    if (MODE==1){ mw[q]=mlin_w[j]; }
  }
  const float mlb = (MODE==1) ? mlin_b[0] : 0.f;

  // ---- init h (own 16 cells) + ps
  #pragma unroll
  for (int q=0;q<2;++q){
    const int j = (w0+q)*16 + l15;
    #pragma unroll
    for (int rt=0;rt<2;++rt)
      #pragma unroll
      for (int r=0;r<4;++r){
        const int row = rt*16 + bi0 + r;
        hbuf[hswz(row, j)] = h_state[(size_t)(b0+row)*256 + j];
        if (MODE==2) ps[row*256 + j] = 0.f;
      }
  }
  if (MODE==0 && tid<32){
    const int t = slice*SL;
    xb[tid] = (t==0) ? dpad[b0+tid] : seq[(size_t)(t-1)*BB + b0 + tid];
  }
  // ---- bootstrap: stage chunk 0 (own 6 fragments) into buf0
  #pragma unroll
  for (int q=0;q<2;++q)
    #pragma unroll
    for (int g=0;g<3;++g){
      const int fo = ((w0+q)*3+g)*1024;
      gload_lds16((const char*)wfrag + fo + (lane<<4), (char*)wbuf + fo);
    }
  __syncthreads();   // drains bootstrap loads

  for (int ts=0; ts<SL; ++ts){
    const int cur = ts & 1;

    // step-top loads: gi (dec, 12 x f16x4) / x prefetch (enc)
    f16x4 gv[2][3][2];
    if (MODE!=0){
      #pragma unroll
      for (int rt=0;rt<2;++rt){
        const size_t tb = ((size_t)ts*16 + (g32*2+rt))*24576u;   // 1536*16
        #pragma unroll
        for (int q=0;q<2;++q)
          #pragma unroll
          for (int g=0;g<3;++g){
            const size_t n = (size_t)(GOFF + g*256 + (w0+q)*16 + l15);
            gv[q][g][rt] = *(const f16x4*)(gi_buf + tb + n*16 + bi0);
          }
      }
    } else if (tid<32 && ts+1<SL){
      xb[(cur^1)*32 + tid] = seq[(size_t)(slice*SL + ts)*BB + b0 + tid];
    }

    // ---- streamed-MFMA phase (r11's pinned fence pattern)
    f32x4 acc[2][3][2];
    #pragma unroll
    for (int q=0;q<2;++q)
      #pragma unroll
      for (int rt=0;rt<2;++rt){
        acc[q][0][rt] = (f32x4){cr[q],cr[q],cr[q],cr[q]};
        acc[q][1][rt] = (f32x4){cz[q],cz[q],cz[q],cz[q]};
        acc[q][2][rt] = (f32x4){cnh[q],cnh[q],cnh[q],cnh[q]};
      }
    #pragma unroll
    for (int k=0;k<8;++k){
      LGKM0_SB();   // prior ds_reads complete -> safe to overwrite their buffer
      {
        const int nk = (k<7) ? (k+1) : 0;
        const char* src = (const char*)wfrag + (size_t)nk*49152u;
        char* dst = (char*)wbuf + (nk&1)*49152;
        #pragma unroll
        for (int q=0;q<2;++q)
          #pragma unroll
          for (int g=0;g<3;++g){
            const int fo = ((w0+q)*3+g)*1024;
            gload_lds16(src + fo + (lane<<4), dst + fo);
          }
      }
      SB();         // prefetch block pinned in issue order
      if (k>0) WAITV6_SB();   // chunk k DMA complete (chunk k+1 in flight)

      const f16* wb = wbuf + (k&1)*24576;
      const int koff = (((k*4+lhi) ^ (l15&7))<<3);
      const f16x8 a0 = *(const f16x8*)(hbuf + (     l15)*256 + koff);
      const f16x8 a1 = *(const f16x8*)(hbuf + (16 + l15)*256 + koff);
      #pragma unroll
      for (int q=0;q<2;++q)
        #pragma unroll
        for (int g=0;g<3;++g){
          const f16x8 b = *(const f16x8*)(wb + (((w0+q)*3+g)*64 + lane)*8);
          acc[q][g][0] = __builtin_amdgcn_mfma_f32_16x16x32_f16(a0, b, acc[q][g][0], 0,0,0);
          acc[q][g][1] = __builtin_amdgcn_mfma_f32_16x16x32_f16(a1, b, acc[q][g][1], 0,0,0);
        }
    }
    __syncthreads();   // #1: all A-reads done -> h safe to overwrite

    // ---- gate phase (in-place h update)
    float mpart[2][4] = {{0,0,0,0},{0,0,0,0}};
    #pragma unroll
    for (int q=0;q<2;++q){
      const int j = (w0+q)*16 + l15;
      #pragma unroll
      for (int rt=0;rt<2;++rt)
        #pragma unroll
        for (int r=0;r<4;++r){
          const int row = rt*16 + bi0 + r;
          const int sz = hswz(row, j);
          const float hprev = (float)hbuf[sz];
          float gir, giz, gin;
          if (MODE==0){
            const float x = xb[cur*32 + row];
            gir = x*wr_[q]; giz = x*wz_[q]; gin = x*wn_[q] + cni[q];
          } else {
            gir = (float)gv[q][0][rt][r];
            giz = (float)gv[q][1][rt][r];
            gin = (float)gv[q][2][rt][r];
          }
          const float rr = sigf(gir + acc[q][0][rt][r]);
          const float zz = sigf(giz + acc[q][1][rt][r]);
          const float nn = tanh_(gin + rr*acc[q][2][rt][r]);
          const float h  = (1.f-zz)*nn + zz*hprev;
          hbuf[sz] = (f16)h;
          if (MODE==0) he_buf[((size_t)ts*BB + (b0+row))*HH + j] = (f16)h;
          if (MODE==1) mpart[rt][r] += h*mw[q];
          if (MODE==2) ps[row*256 + j] += h;
        }
    }
    if (MODE==1){
      #pragma unroll
      for (int m=1;m<16;m<<=1)
        #pragma unroll
        for (int rt=0;rt<2;++rt)
          #pragma unroll
          for (int r=0;r<4;++r) mpart[rt][r] += __shfl_xor(mpart[rt][r], m, 64);
      if (l15==0){
        #pragma unroll
        for (int rt=0;rt<2;++rt)
          #pragma unroll
          for (int r=0;r<4;++r) mred[wid*32 + rt*16 + bi0 + r] = mpart[rt][r];
      }
    }
    __syncthreads();   // #2: new h + mred published
    if (MODE==1 && tid<32){
      float v = mlb;
      #pragma unroll
      for (int w=0;w<8;++w) v += mred[w*32 + tid];
      out_mask[(size_t)(slice*SL + ts)*BB + b0 + tid] = v;
    }
  }

  // ---- writebacks (own 16 cells)
  #pragma unroll
  for (int q=0;q<2;++q){
    const int j = (w0+q)*16 + l15;
    #pragma unroll
    for (int rt=0;rt<2;++rt)
      #pragma unroll
      for (int r=0;r<4;++r){
        const int row = rt*16 + bi0 + r;
        h_state[(size_t)(b0+row)*256 + j] = hbuf[hswz(row, j)];
        if (MODE==2){
          const size_t idx = (size_t)(b0+row)*256 + j;
          hpsum[idx] = hpsum[idx] + ps[row*256 + j];
        }
      }
  }
}

// 24 blocks: rec = bid>>3 (0 mdec, 1 pdec, 2 enc), g32 = bid&7 (row group).
// bid%8 spreads the 8 row-groups across XCDs; each XCD hosts one WG of
// each rec -> all three weight buffers stay L2-resident per XCD.
__global__ __launch_bounds__(512) void rec_kernel(
  const float* __restrict__ seq, const float* __restrict__ dpad,
  const float* __restrict__ enc_wih, const float* __restrict__ enc_bih, const float* __restrict__ enc_bhh,
  const float* __restrict__ mdec_bhh, const float* __restrict__ pdec_bhh,
  const float* __restrict__ mlin_w, const float* __restrict__ mlin_b,
  const f16* __restrict__ wfrag_enc, const f16* __restrict__ wfrag_m, const f16* __restrict__ wfrag_p,
  f16* __restrict__ he_st, f16* __restrict__ hm_st, f16* __restrict__ hp_st,
  f16* __restrict__ he_buf, const f16* __restrict__ gi_buf,
  float* __restrict__ hpsum, float* __restrict__ out_mask,
  int dec_slice, int enc_slice, int SL)
{
  __shared__ __align__(16) unsigned char smem[148736];
  const int rec = blockIdx.x >> 3, g32 = blockIdx.x & 7;
  if (rec == 0){
    if (dec_slice < 0) return;
    gru_run<1>(g32, dec_slice, SL, wfrag_m, nullptr, mdec_bhh, nullptr, nullptr, nullptr,
               gi_buf, hm_st, nullptr, mlin_w, mlin_b, out_mask, nullptr, smem);
  } else if (rec == 1){
    if (dec_slice < 0) return;
    gru_run<2>(g32, dec_slice, SL, wfrag_p, nullptr, pdec_bhh, nullptr, nullptr, nullptr,
               gi_buf, hp_st, nullptr, nullptr, nullptr, nullptr, hpsum, smem);
  } else {
    if (enc_slice < 0) return;
    gru_run<0>(g32, enc_slice, SL, wfrag_enc, enc_bih, enc_bhh, enc_wih, seq, dpad,
               nullptr, he_st, he_buf, nullptr, nullptr, nullptr, nullptr, smem);
  }
}

// =====================================================================
// GI: gi[t][b][n] = he[t][b][:] . w_ih_cat[n][:] + bih_cat[n]
// =====================================================================
__global__ __launch_bounds__(256,4) void gi_kernel(
  const f16* __restrict__ he_buf, const f16* __restrict__ wfrag_gi,
  const float* __restrict__ mdec_bih, const float* __restrict__ pdec_bih,
  f16* __restrict__ gi_buf)
{
  const int ts = blockIdx.x >> 2;
  const int bq = blockIdx.x & 3;
  const int tid = threadIdx.x, lane = tid&63, wid = tid>>6;
  const int l15 = lane&15, lhi = lane>>4;
  __shared__ f16 het[64*264];
  {
    const uint4* src = (const uint4*)(he_buf + ((size_t)ts*BB + bq*64)*HH);
    uint4* dst = (uint4*)het;
    #pragma unroll
    for (int k=0;k<8;++k){
      const int i = tid + k*256;
      dst[(i>>5)*33 + (i&31)] = src[i];
    }
  }
  __syncthreads();
  for (int mi=0; mi<24; ++mi){
    const int mt = wid*24 + mi;
    const int row0 = mt*16 + lhi*4;
    float bb[4];
    #pragma unroll
    for (int r=0;r<4;++r){
      const int rw = row0 + r;
      bb[r] = (rw < 768) ? mdec_bih[rw] : pdec_bih[rw-768];
    }
    f32x4 acc[4] = {{0,0,0,0},{0,0,0,0},{0,0,0,0},{0,0,0,0}};
    #pragma unroll
    for (int ks=0;ks<8;++ks){
      const f16x8 a = *(const f16x8*)(wfrag_gi + ((size_t)(mt*8+ks)*64 + lane)*8);
      #pragma unroll
      for (int bt=0;bt<4;++bt){
        const f16x8 b = *(const f16x8*)(het + (bt*16+l15)*264 + ks*32 + lhi*8);
        acc[bt] = __builtin_amdgcn_mfma_f32_16x16x32_f16(a, b, acc[bt], 0,0,0);
      }
    }
    #pragma unroll
    for (int bt=0;bt<4;++bt){
      const int btg = bq*4 + bt;
      const size_t base = (((size_t)ts*16 + btg)*1536 + (size_t)mt*16 + lhi*4)*16 + l15;
      #pragma unroll
      for (int r=0;r<4;++r) gi_buf[base + (size_t)r*16] = (f16)(acc[bt][r] + bb[r]);
    }
  }
}

// =====================================================================
// PRED: pred[b][p] = (hpsum[b]/512) . plin_w[p] + plin_b[p]
// =====================================================================
__global__ __launch_bounds__(256,1) void pred_kernel(
  const float* __restrict__ hpsum, const float* __restrict__ plin_w,
  const float* __restrict__ plin_b, float* __restrict__ out)
{
  __shared__ float hs[256];
  const int p = threadIdx.x;
  const float bias = plin_b[p];
  for (int bb=0; bb<4; ++bb){
    const int b = blockIdx.x*4 + bb;
    __syncthreads();
    hs[p] = hpsum[(size_t)b*256 + p];
    __syncthreads();
    float acc = 0.f;
    const float4* wrow = (const float4*)(plin_w + (size_t)p*256);
    #pragma unroll 4
    for (int k4=0;k4<64;++k4){
      const float4 w = wrow[k4];
      acc += hs[k4*4+0]*w.x + hs[k4*4+1]*w.y + hs[k4*4+2]*w.z + hs[k4*4+3]*w.w;
    }
    out[131072 + (size_t)b*256 + p] = acc*(1.f/512.f) + bias;
  }
}

// =====================================================================
extern "C" void kernel_launch(void* const* d_in, const int* in_sizes, int n_in,
                              void* d_out, int out_size, void* d_ws, size_t ws_size,
                              hipStream_t stream)
{
  const float* seq      = (const float*)d_in[0];
  const float* dpad     = (const float*)d_in[1];
  const float* h0e      = (const float*)d_in[2];
  const float* h0m      = (const float*)d_in[3];
  const float* h0p      = (const float*)d_in[4];
  const float* enc_wih  = (const float*)d_in[5];
  const float* enc_whh  = (const float*)d_in[6];
  const float* enc_bih  = (const float*)d_in[7];
  const float* enc_bhh  = (const float*)d_in[8];
  const float* mdec_wih = (const float*)d_in[9];
  const float* mdec_whh = (const float*)d_in[10];
  const float* mdec_bih = (const float*)d_in[11];
  const float* mdec_bhh = (const float*)d_in[12];
  const float* mlin_w   = (const float*)d_in[13];
  const float* mlin_b   = (const float*)d_in[14];
  const float* pdec_wih = (const float*)d_in[15];
  const float* pdec_whh = (const float*)d_in[16];
  const float* pdec_bih = (const float*)d_in[17];
  const float* pdec_bhh = (const float*)d_in[18];
  const float* plin_w   = (const float*)d_in[19];
  const float* plin_b   = (const float*)d_in[20];
  float* out = (float*)d_out;

  char* ws = (char*)d_ws;
  f16* wfrag_enc = (f16*)(ws + O_WFRAG_ENC);
  f16* wfrag_m   = (f16*)(ws + O_WFRAG_M);
  f16* wfrag_p   = (f16*)(ws + O_WFRAG_P);
  f16* wfrag_gi  = (f16*)(ws + O_WFRAG_GI);
  f16* he_st     = (f16*)(ws + O_HE_ST);
  f16* hm_st     = (f16*)(ws + O_HM_ST);
  f16* hp_st     = (f16*)(ws + O_HP_ST);
  float* hpsum   = (float*)(ws + O_HPSUM);

  int SL = 64;
  while (SL > 1 && (size_t)O_DYN + (size_t)SL*DYN_PER_STEP > ws_size) SL >>= 1;
  const int S = TT / SL;
  f16* he_buf = (f16*)(ws + O_DYN);
  f16* gi_buf = (f16*)(ws + O_DYN + (size_t)SL*131072u);

  prep_kernel<<<dim3(4096), dim3(256), 0, stream>>>(
      enc_whh, mdec_whh, pdec_whh, mdec_wih, pdec_wih, h0e, h0m, h0p,
      wfrag_enc, wfrag_m, wfrag_p, wfrag_gi, he_st, hm_st, hp_st, hpsum);

  // encoder slice 0 only
  rec_kernel<<<dim3(24), dim3(512), 0, stream>>>(
      seq, dpad, enc_wih, enc_bih, enc_bhh, mdec_bhh, pdec_bhh,
      mlin_w, mlin_b, wfrag_enc, wfrag_m, wfrag_p, he_st, hm_st, hp_st,
      he_buf, gi_buf, hpsum, out, -1, 0, SL);
  gi_kernel<<<dim3(SL*4), dim3(256), 0, stream>>>(he_buf, wfrag_gi, mdec_bih, pdec_bih, gi_buf);

  for (int s=0; s<S; ++s){
    const int enc_s = (s+1 < S) ? (s+1) : -1;
    rec_kernel<<<dim3(24), dim3(512), 0, stream>>>(
        seq, dpad, enc_wih, enc_bih, enc_bhh, mdec_bhh, pdec_bhh,
        mlin_w, mlin_b, wfrag_enc, wfrag_m, wfrag_p, he_st, hm_st, hp_st,
        he_buf, gi_buf, hpsum, out, s, enc_s, SL);
    if (enc_s >= 0)
      gi_kernel<<<dim3(SL*4), dim3(256), 0, stream>>>(he_buf, wfrag_gi, mdec_bih, pdec_bih, gi_buf);
  }

  pred_kernel<<<dim3(64), dim3(256), 0, stream>>>(hpsum, plin_w, plin_b, out);
}